// Round 9
// baseline (1227.887 us; speedup 1.0000x reference)
//
#include <hip/hip_runtime.h>

#define N_USERS 100000
#define N_ITEMS 50000
#define N_NODES 150000
#define DIM     32
#define N_EDGES 2400000
#define K_STEPS 10
#define MID     75000      // src split: lo pass covers src<MID (2.4 MB fp8 mirror half)

#define WDEQ 3.814697265625e-06f   // 2^-18

#define CH   4096      // edges per dscatter workgroup
#define NSB  147       // dst buckets: dst >> 10
#define NSBP 160       // padded

typedef float v2f __attribute__((ext_vector_type(2)));

// ---------------- helpers: bf16 / fp8 ----------------
__device__ __forceinline__ float bflo(unsigned u) { return __uint_as_float(u << 16); }
__device__ __forceinline__ float bfhi(unsigned u) { return __uint_as_float(u & 0xffff0000u); }
__device__ __forceinline__ unsigned packbf(float a, float b) {   // RNE pack
    unsigned ua = __float_as_uint(a), ub = __float_as_uint(b);
    ua += 0x7fffu + ((ua >> 16) & 1u);
    ub += 0x7fffu + ((ub >> 16) & 1u);
    return (ua >> 16) | (ub & 0xffff0000u);
}
__device__ __forceinline__ unsigned pack_fp8x4(float a, float b, float c, float d) {
    unsigned r = 0;
    r = __builtin_amdgcn_cvt_pk_fp8_f32(a, b, r, false);   // bytes 0,1
    r = __builtin_amdgcn_cvt_pk_fp8_f32(c, d, r, true);    // bytes 2,3
    return r;
}
#define UNPACK_FP8X4(d, f0, f1, f2, f3)                          \
    { v2f _lo = __builtin_amdgcn_cvt_pk_f32_fp8((d), false);     \
      v2f _hi = __builtin_amdgcn_cvt_pk_f32_fp8((d), true);      \
      f0 = _lo[0]; f1 = _lo[1]; f2 = _hi[0]; f3 = _hi[1]; }

// unroll-4 + remainder edge loop accumulating into a0..a3 from fp8 mirror MIR
#define GATHER_LOOP(MIR)                                                   \
    for (; j + 4 <= end; j += 4) {                                         \
        unsigned e0 = __builtin_nontemporal_load(csr + j);                 \
        unsigned e1 = __builtin_nontemporal_load(csr + j + 1);             \
        unsigned e2 = __builtin_nontemporal_load(csr + j + 2);             \
        unsigned e3 = __builtin_nontemporal_load(csr + j + 3);             \
        float w0 = (float)(e0 & 0x3fffu) * WDEQ;                           \
        float w1 = (float)(e1 & 0x3fffu) * WDEQ;                           \
        float w2 = (float)(e2 & 0x3fffu) * WDEQ;                           \
        float w3 = (float)(e3 & 0x3fffu) * WDEQ;                           \
        unsigned d0 = MIR[((e0 >> 14) << 3) + q];                          \
        unsigned d1 = MIR[((e1 >> 14) << 3) + q];                          \
        unsigned d2 = MIR[((e2 >> 14) << 3) + q];                          \
        unsigned d3 = MIR[((e3 >> 14) << 3) + q];                          \
        float f0, f1, f2, f3;                                              \
        UNPACK_FP8X4(d0, f0, f1, f2, f3);                                  \
        a0 = fmaf(w0, f0, a0); a1 = fmaf(w0, f1, a1);                      \
        a2 = fmaf(w0, f2, a2); a3 = fmaf(w0, f3, a3);                      \
        UNPACK_FP8X4(d1, f0, f1, f2, f3);                                  \
        a0 = fmaf(w1, f0, a0); a1 = fmaf(w1, f1, a1);                      \
        a2 = fmaf(w1, f2, a2); a3 = fmaf(w1, f3, a3);                      \
        UNPACK_FP8X4(d2, f0, f1, f2, f3);                                  \
        a0 = fmaf(w2, f0, a0); a1 = fmaf(w2, f1, a1);                      \
        a2 = fmaf(w2, f2, a2); a3 = fmaf(w2, f3, a3);                      \
        UNPACK_FP8X4(d3, f0, f1, f2, f3);                                  \
        a0 = fmaf(w3, f0, a0); a1 = fmaf(w3, f1, a1);                      \
        a2 = fmaf(w3, f2, a2); a3 = fmaf(w3, f3, a3);                      \
    }                                                                      \
    for (; j < end; ++j) {                                                 \
        unsigned e0 = __builtin_nontemporal_load(csr + j);                 \
        float w0 = (float)(e0 & 0x3fffu) * WDEQ;                           \
        unsigned d0 = MIR[((e0 >> 14) << 3) + q];                          \
        float f0, f1, f2, f3;                                              \
        UNPACK_FP8X4(d0, f0, f1, f2, f3);                                  \
        a0 = fmaf(w0, f0, a0); a1 = fmaf(w0, f1, a1);                      \
        a2 = fmaf(w0, f2, a2); a3 = fmaf(w0, f3, a3);                      \
    }

// ---------------- norm reduction: max over rows of sum(x^2) ----------------
__global__ void norm_kernel(const float* __restrict__ xu, const float* __restrict__ xi,
                            unsigned int* __restrict__ norm_bits) {
    int gid = blockIdx.x * blockDim.x + threadIdx.x;
    int row = gid >> 3;
    int q   = gid & 7;
    float s = 0.0f;
    if (row < N_NODES) {
        const float* x = (row < N_USERS) ? (xu + (size_t)row * DIM)
                                         : (xi + (size_t)(row - N_USERS) * DIM);
        float4 v = *(const float4*)(x + q * 4);
        s = v.x * v.x + v.y * v.y + v.z * v.z + v.w * v.w;
    }
    s += __shfl_xor(s, 1);
    s += __shfl_xor(s, 2);
    s += __shfl_xor(s, 4);
    s = fmaxf(s, __shfl_xor(s, 8));
    s = fmaxf(s, __shfl_xor(s, 16));
    s = fmaxf(s, __shfl_xor(s, 32));
    __shared__ float smax[4];
    int wave = threadIdx.x >> 6;
    if ((threadIdx.x & 63) == 0) smax[wave] = s;
    __syncthreads();
    if (threadIdx.x == 0) {
        float m = fmaxf(fmaxf(smax[0], smax[1]), fmaxf(smax[2], smax[3]));
        atomicMax(norm_bits, __float_as_uint(m));   // non-neg: uint order == float order
    }
}

// ------- dst-bucket histogram (grid-strided, LDS-aggregated) ---------------
__global__ void ebh_kernel(const int* __restrict__ ed, int* __restrict__ ebh) {
    __shared__ int lc[NSBP];
    if (threadIdx.x < NSBP) lc[threadIdx.x] = 0;
    __syncthreads();
    int stride = gridDim.x * blockDim.x;
    for (int e = blockIdx.x * blockDim.x + threadIdx.x; e < N_EDGES; e += stride)
        atomicAdd(&lc[(unsigned)ed[e] >> 10], 1);
    __syncthreads();
    if (threadIdx.x < NSBP && lc[threadIdx.x]) atomicAdd(&ebh[threadIdx.x], lc[threadIdx.x]);
}

// ---- exclusive scan of bucket counts -> sbase (with sentinel), scursor ----
__global__ void sscan_kernel(const int* __restrict__ ebh,
                             int* __restrict__ sbase, int* __restrict__ scursor) {
    __shared__ int buf[256];
    int tid = threadIdx.x;
    int v = (tid < NSB) ? ebh[tid] : 0;
    buf[tid] = v;
    __syncthreads();
    for (int off = 1; off < 256; off <<= 1) {
        int t = (tid >= off) ? buf[tid - off] : 0;
        __syncthreads();
        buf[tid] += t;
        __syncthreads();
    }
    int ex = buf[tid] - v;
    if (tid <= NSB) sbase[tid] = ex;      // sbase[NSB] == N_EDGES (sentinel)
    if (tid < NSB)  scursor[tid] = ex;
}

// --- LDS-staged coalesced scatter: edges -> E1, bucketed by dst>>10 --------
// E1[k] = { csrword = src<<14 | q14,  dst }   (src < 2^18: exact 32-bit fit)
__global__ __launch_bounds__(256) void dscatter_kernel(
        const int* __restrict__ es, const int* __restrict__ ed,
        const float* __restrict__ ew,
        int* __restrict__ scursor, uint2* __restrict__ E1) {
    __shared__ int hist[NSBP];
    __shared__ int start[NSBP];
    __shared__ int lcur[NSBP];
    __shared__ int gbase[NSBP];
    __shared__ uint2 stage[CH];
    __shared__ unsigned char sbkt[CH];
    __shared__ int buf[256];
    int tid = threadIdx.x;
    int base0 = blockIdx.x * CH;
    int count = N_EDGES - base0;
    if (count > CH) count = CH;
    if (tid < NSBP) hist[tid] = 0;
    __syncthreads();
    for (int k = tid; k < count; k += 256)
        atomicAdd(&hist[(unsigned)ed[base0 + k] >> 10], 1);
    __syncthreads();
    int v = (tid < NSBP) ? hist[tid] : 0;
    buf[tid] = v;
    __syncthreads();
    for (int off = 1; off < 256; off <<= 1) {
        int t = (tid >= off) ? buf[tid - off] : 0;
        __syncthreads();
        buf[tid] += t;
        __syncthreads();
    }
    if (tid < NSBP) { start[tid] = buf[tid] - v; lcur[tid] = buf[tid] - v; }
    __syncthreads();
    for (int k = tid; k < count; k += 256) {
        int e = base0 + k;
        int dst = ed[e];
        int b   = (unsigned)dst >> 10;
        unsigned q = (unsigned)(ew[e] * 262144.0f + 0.5f);   // w in [0,1/16): q < 16384
        if (q > 16383u) q = 16383u;
        uint2 p;
        p.x = ((unsigned)es[e] << 14) | q;
        p.y = (unsigned)dst;
        int lp = atomicAdd(&lcur[b], 1);
        stage[lp] = p;
        sbkt[lp] = (unsigned char)b;
    }
    __syncthreads();
    if (tid < NSBP) gbase[tid] = hist[tid] ? atomicAdd(&scursor[tid], hist[tid]) : 0;
    __syncthreads();
    for (int k = tid; k < count; k += 256) {
        int b = sbkt[k];
        E1[gbase[b] + (k - start[b])] = stage[k];
    }
}

// --- bucket build: degrees (lo/hi split) + row offsets + CSR fill, all local
__global__ __launch_bounds__(256) void bucket_build_kernel(
        const uint2* __restrict__ E1, const int* __restrict__ sbase,
        int* __restrict__ prow, int* __restrict__ prowMid,
        unsigned* __restrict__ csr) {
    __shared__ int lo[1024], hi[1024];
    __shared__ int wsum[4];
    int b   = blockIdx.x;
    int tid = threadIdx.x;
    int r0  = b << 10;
    int nr  = N_NODES - r0; if (nr > 1024) nr = 1024;
    for (int r = tid; r < 1024; r += 256) { lo[r] = 0; hi[r] = 0; }
    __syncthreads();
    int segbase = sbase[b];
    int segend  = sbase[b + 1];
    for (int k = segbase + tid; k < segend; k += 256) {
        uint2 p = E1[k];
        int r = (int)p.y - r0;
        if ((p.x >> 14) < (unsigned)MID) atomicAdd(&lo[r], 1);
        else                             atomicAdd(&hi[r], 1);
    }
    __syncthreads();
    // exclusive scan of per-row totals (4 rows per thread)
    int rr = tid << 2;
    int l0 = lo[rr], l1 = lo[rr+1], l2 = lo[rr+2], l3 = lo[rr+3];
    int h0 = hi[rr], h1 = hi[rr+1], h2 = hi[rr+2], h3 = hi[rr+3];
    int t0 = l0+h0, t1 = l1+h1, t2 = l2+h2, t3 = l3+h3;
    int s = t0 + t1 + t2 + t3;
    int lane = tid & 63;
    int inc = s;
    for (int off = 1; off < 64; off <<= 1) {
        int t = __shfl_up(inc, off);
        if (lane >= off) inc += t;
    }
    int wave = tid >> 6;
    if (lane == 63) wsum[wave] = inc;
    __syncthreads();
    int woff = 0;
    for (int w = 0; w < wave; ++w) woff += wsum[w];
    int excl = woff + inc - s;
    int rs0 = segbase + excl;
    int rs1 = rs0 + t0;
    int rs2 = rs1 + t1;
    int rs3 = rs2 + t2;
    if (rr + 0 < nr) { prow[r0+rr+0] = rs0; prowMid[r0+rr+0] = rs0 + l0; }
    if (rr + 1 < nr) { prow[r0+rr+1] = rs1; prowMid[r0+rr+1] = rs1 + l1; }
    if (rr + 2 < nr) { prow[r0+rr+2] = rs2; prowMid[r0+rr+2] = rs2 + l2; }
    if (rr + 3 < nr) { prow[r0+rr+3] = rs3; prowMid[r0+rr+3] = rs3 + l3; }
    lo[rr+0] = rs0; hi[rr+0] = rs0 + l0;
    lo[rr+1] = rs1; hi[rr+1] = rs1 + l1;
    lo[rr+2] = rs2; hi[rr+2] = rs2 + l2;
    lo[rr+3] = rs3; hi[rr+3] = rs3 + l3;
    if (b == NSB - 1 && tid == 0) prow[N_NODES] = N_EDGES;
    __syncthreads();
    // ticket fill: lo entries first, hi entries after prowMid
    for (int k = segbase + tid; k < segend; k += 256) {
        uint2 p = E1[k];
        int r = (int)p.y - r0;
        int pos = ((p.x >> 14) < (unsigned)MID) ? atomicAdd(&lo[r], 1)
                                                : atomicAdd(&hi[r], 1);
        csr[pos] = p.x;
    }
}

// --- init: h(d_out) = x/norm; fp8 mirror h8p; bf16 static mirror (node order)
__global__ void init_kernel(const float* __restrict__ xu, const float* __restrict__ xi,
                            const float* __restrict__ su, const float* __restrict__ si,
                            const unsigned int* __restrict__ norm_bits,
                            float* __restrict__ h, unsigned* __restrict__ h8p,
                            uint2* __restrict__ stu2) {
    int gid = blockIdx.x * blockDim.x + threadIdx.x;
    int d = gid >> 3;
    int q = gid & 7;
    if (d >= N_NODES) return;
    float rn = rsqrtf(__uint_as_float(*norm_bits));
    int fbase = d * DIM + (q << 2);
    const float* x = (d < N_USERS) ? (xu + fbase) : (xi + fbase - N_USERS * DIM);
    const float* s = (d < N_USERS) ? (su + fbase) : (si + fbase - N_USERS * DIM);
    float4 v = *(const float4*)x;
    v.x *= rn; v.y *= rn; v.z *= rn; v.w *= rn;
    *(float4*)(h + fbase) = v;
    h8p[(d << 3) + q] = pack_fp8x4(v.x, v.y, v.z, v.w);
    float4 sv = *(const float4*)s;
    uint2 sp;
    sp.x = packbf(sv.x * rn, sv.y * rn);
    sp.y = packbf(sv.z * rn, sv.w * rn);
    stu2[(d << 3) + q] = sp;
}

// ---- pass lo: partial gather over src<MID (2.4 MB L2-resident window) -----
__global__ void gather_lo_kernel(const unsigned* __restrict__ mir,
                                 unsigned long long* __restrict__ t16,
                                 const unsigned* __restrict__ csr,
                                 const int* __restrict__ prow,
                                 const int* __restrict__ prowMid) {
    int gid = blockIdx.x * blockDim.x + threadIdx.x;
    int i = gid >> 3;
    int q = gid & 7;
    if (i >= N_NODES) return;
    int j   = prow[i];
    int end = prowMid[i];
    float a0 = 0, a1 = 0, a2 = 0, a3 = 0;
    GATHER_LOOP(mir)
    unsigned long long v = (unsigned long long)packbf(a0, a1)
                         | ((unsigned long long)packbf(a2, a3) << 32);
    __builtin_nontemporal_store(v, t16 + (i << 3) + q);
}

// ---- pass hi (hop 1): add src>=MID, write t8p fp8 --------------------------
__global__ void gather_hi_pack_kernel(const unsigned* __restrict__ mir,
                                      const unsigned long long* __restrict__ t16,
                                      unsigned* __restrict__ t8p,
                                      const unsigned* __restrict__ csr,
                                      const int* __restrict__ prow,
                                      const int* __restrict__ prowMid) {
    int gid = blockIdx.x * blockDim.x + threadIdx.x;
    int i = gid >> 3;
    int q = gid & 7;
    if (i >= N_NODES) return;
    int j   = prowMid[i];
    int end = prow[i + 1];
    float a0 = 0, a1 = 0, a2 = 0, a3 = 0;
    GATHER_LOOP(mir)
    unsigned long long v = __builtin_nontemporal_load(t16 + (i << 3) + q);
    a0 += bflo((unsigned)v);         a1 += bfhi((unsigned)v);
    a2 += bflo((unsigned)(v >> 32)); a3 += bfhi((unsigned)(v >> 32));
    t8p[(i << 3) + q] = pack_fp8x4(a0, a1, a2, a3);
}

// ---- pass hi (hop 2): add src>=MID, fuse ODE update; h fp32 in d_out ------
__global__ void gather_hi_update_kernel(const unsigned* __restrict__ mir,
                                        const unsigned long long* __restrict__ t16,
                                        float* __restrict__ h,
                                        unsigned* __restrict__ h8p,
                                        const unsigned* __restrict__ csr,
                                        const int* __restrict__ prow,
                                        const int* __restrict__ prowMid,
                                        const uint2* __restrict__ stu2,
                                        const float* __restrict__ alpha_logit,
                                        const float* __restrict__ dt) {
    int gid = blockIdx.x * blockDim.x + threadIdx.x;
    int i = gid >> 3;
    int q = gid & 7;
    if (i >= N_NODES) return;
    int j   = prowMid[i];
    int end = prow[i + 1];
    float a0 = 0, a1 = 0, a2 = 0, a3 = 0;
    GATHER_LOOP(mir)
    unsigned long long v = __builtin_nontemporal_load(t16 + (i << 3) + q);
    a0 += bflo((unsigned)v);         a1 += bfhi((unsigned)v);
    a2 += bflo((unsigned)(v >> 32)); a3 += bfhi((unsigned)(v >> 32));
    float step = dt[0] * (1.0f / K_STEPS);
    float al = 1.0f / (1.0f + __expf(-alpha_logit[i]));
    int fbase = i * DIM + (q << 2);
    float4 hv = *(const float4*)(h + fbase);
    uint2 sp = stu2[(i << 3) + q];
    hv.x += step * (a0 - al * hv.x + bflo(sp.x));
    hv.y += step * (a1 - al * hv.y + bfhi(sp.x));
    hv.z += step * (a2 - al * hv.z + bflo(sp.y));
    hv.w += step * (a3 - al * hv.w + bfhi(sp.y));
    *(float4*)(h + fbase) = hv;
    h8p[(i << 3) + q] = pack_fp8x4(hv.x, hv.y, hv.z, hv.w);
}

extern "C" void kernel_launch(void* const* d_in, const int* in_sizes, int n_in,
                              void* d_out, int out_size, void* d_ws, size_t ws_size,
                              hipStream_t stream) {
    const float* xu          = (const float*)d_in[0];
    const float* xi          = (const float*)d_in[1];
    const float* su          = (const float*)d_in[2];
    const float* si          = (const float*)d_in[3];
    const float* ew          = (const float*)d_in[4];
    const float* alpha_logit = (const float*)d_in[5];
    const float* dt          = (const float*)d_in[6];
    const int*   es          = (const int*)d_in[7];
    const int*   ed          = (const int*)d_in[8];
    float* h = (float*)d_out;                     // fp32 h lives in d_out (node order)

    // ---- workspace layout (~40.6 MB peak) ----
    char* base = (char*)d_ws;
    unsigned int* norm_bits = (unsigned int*)base;            // 4 B
    int* sbase   = (int*)(base + 64);                         // 168 ints (sentinel)
    int* scursor = (int*)(base + 1024);                       // 160 ints
    int* ebh     = (int*)(base + 2048);                       // 160 ints
    const size_t SLOT = 640 * 1024;
    int* prow    = (int*)(base + 4096 + 0 * SLOT);            // N_NODES+1
    int* prowMid = (int*)(base + 4096 + 1 * SLOT);            // N_NODES
    unsigned* csr = (unsigned*)(base + 1536u * 1024);         // 9.6 MB -> ends 11.1 MB
    // union region @11.5 MB: E1 (19.2 MB, dead after bucket_build) / mirrors
    char* region = base + 11776u * 1024;
    uint2*    E1   = (uint2*)region;                          // 19.2 MB
    unsigned* t8p  = (unsigned*)region;                       // 4.8 MB
    unsigned* h8p  = t8p + (size_t)N_NODES * 8;               // 4.8 MB
    uint2*    stu2 = (uint2*)(h8p + (size_t)N_NODES * 8);     // 9.6 MB
    unsigned long long* t16 = (unsigned long long*)(base + 31744u * 1024);  // 9.6 MB bf16 partials

    hipMemsetAsync(norm_bits, 0, sizeof(unsigned int), stream);
    hipMemsetAsync(ebh, 0, NSBP * sizeof(int), stream);

    const int node8b = (N_NODES * 8 + 255) / 256;
    const int chb    = (N_EDGES + CH - 1) / CH;   // 586

    norm_kernel<<<node8b, 256, 0, stream>>>(xu, xi, norm_bits);
    ebh_kernel<<<586, 256, 0, stream>>>(ed, ebh);
    sscan_kernel<<<1, 256, 0, stream>>>(ebh, sbase, scursor);
    dscatter_kernel<<<chb, 256, 0, stream>>>(es, ed, ew, scursor, E1);
    bucket_build_kernel<<<NSB, 256, 0, stream>>>(E1, sbase, prow, prowMid, csr);
    // init AFTER bucket_build: mirrors overwrite E1's region
    init_kernel<<<node8b, 256, 0, stream>>>(xu, xi, su, si, norm_bits, h, h8p, stu2);

    for (int k = 0; k < K_STEPS; ++k) {
        gather_lo_kernel<<<node8b, 256, 0, stream>>>(h8p, t16, csr, prow, prowMid);
        gather_hi_pack_kernel<<<node8b, 256, 0, stream>>>(h8p, t16, t8p, csr, prow, prowMid);
        gather_lo_kernel<<<node8b, 256, 0, stream>>>(t8p, t16, csr, prow, prowMid);
        gather_hi_update_kernel<<<node8b, 256, 0, stream>>>(t8p, t16, h, h8p, csr, prow,
                                                            prowMid, stu2, alpha_logit, dt);
    }
}